// Round 2
// baseline (12039.348 us; speedup 1.0000x reference)
//
#include <hip/hip_runtime.h>
#include <stdint.h>

// ---------------------------------------------------------------------------
// Encoder_Processor round 2: one WG per pipeline stage (M=64), 8 WGs x 512 thr.
// Stage 0 = embedding, 1..7 = recurrent levels. f16 inter-level exchange,
// fp32 h-state in registers, weights pre-packed to MFMA B-frag order (L2-
// resident), forward-only flag sync via agent-scope atomics (L3; L2 never
// invalidated so weights stay cached).
// ---------------------------------------------------------------------------

typedef _Float16 f16x8 __attribute__((ext_vector_type(8)));
typedef float    f32x4 __attribute__((ext_vector_type(4)));

static constexpr int SS     = 256;
static constexpr int BB     = 64;
static constexpr int DIN    = 256;
static constexpr int DH     = 256;
static constexpr int DINNER = 512;
static constexpr int DA     = 64;

// workspace layout (bytes)
static constexpr size_t OFF_FLAGS = 0;
static constexpr size_t OFF_WEMB  = 4096;
static constexpr size_t SZ_WEMB   = (size_t)DIN * DH * 2;       // 128K
static constexpr size_t OFF_W     = OFF_WEMB + SZ_WEMB;
static constexpr size_t SZ_W      = (size_t)DH * DINNER * 2;    // 256K
static constexpr size_t OFF_U     = OFF_W + SZ_W;
static constexpr size_t OFF_W1    = OFF_U + SZ_W;
static constexpr size_t SZ_W1     = (size_t)DINNER * DH * 2;    // 256K
static constexpr size_t OFF_WA1   = OFF_W1 + SZ_W1;
static constexpr size_t SZ_WA1    = (size_t)DH * DA * 2;        // 32K
static constexpr size_t OFF_UA1   = OFF_WA1 + SZ_WA1;
static constexpr size_t OFF_HBUF  = (size_t)1 << 20;
static constexpr size_t SZ_HBUF   = (size_t)SS * BB * DH * 2;   // 8MB (f16)
static constexpr size_t OFF_NM    = OFF_HBUF + 7 * SZ_HBUF;
static constexpr size_t SZ_NM     = (size_t)SS * BB * 4;        // 64KB
static constexpr size_t OFF_HV    = OFF_NM + 7 * SZ_NM;
static constexpr size_t WS_NEEDED = OFF_HV + 7 * SZ_NM;

__device__ __forceinline__ float lrelu(float v) { return v >= 0.0f ? v : 0.01f * v; }

// A-frag LDS address (in halves) for element (kq = k>>3, s); row padded to 65
// frags so strided writes spread across banks (4-way instead of 32-way).
__device__ __forceinline__ int aoff(int kq, int s) { return (kq * 65 + s) * 8; }

// agent-scope data plane (bypasses L1/L2, coherence point = L3)
__device__ __forceinline__ float gldf(const float* p) {
  return __hip_atomic_load((float*)p, __ATOMIC_RELAXED, __HIP_MEMORY_SCOPE_AGENT);
}
__device__ __forceinline__ void gstf(float* p, float v) {
  __hip_atomic_store(p, v, __ATOMIC_RELAXED, __HIP_MEMORY_SCOPE_AGENT);
}
__device__ __forceinline__ void gsth(_Float16* p, _Float16 v) {
  __hip_atomic_store(p, v, __ATOMIC_RELAXED, __HIP_MEMORY_SCOPE_AGENT);
}
__device__ __forceinline__ unsigned long long gld64(const _Float16* p) {
  return __hip_atomic_load((const unsigned long long*)p, __ATOMIC_RELAXED,
                           __HIP_MEMORY_SCOPE_AGENT);
}

// ---------------------------------------------------------------------------
__global__ void zero_flags_k(unsigned* f) {
  if (threadIdx.x < 1024) f[threadIdx.x] = 0u;
}

// pack fp32 row-major [K][N] into f16 MFMA B-frag order:
// frag addr = (((kt*(N/16) + nt)*4 + q)*16 + l)*8 + j ; k = kt*32+q*8+j, n = nt*16+l
__global__ void pack_weight_k(const float* __restrict__ src, _Float16* __restrict__ dst,
                              int K, int N) {
  int idx = blockIdx.x * 256 + threadIdx.x;
  if (idx >= K * N) return;
  int k = idx / N, n = idx - k * N;
  int kt = k >> 5, q = (k >> 3) & 3, j = k & 7;
  int nt = n >> 4, l = n & 15;
  size_t p = (((size_t)(kt * (N >> 4) + nt) * 4 + q) * 16 + l) * 8 + j;
  dst[p] = (_Float16)src[idx];
}

// ---------------------------------------------------------------------------
// persistent pipeline: 8 blocks x 512 threads (8 waves, 2/SIMD)
// ---------------------------------------------------------------------------
__global__ __launch_bounds__(512, 2) void pipeline_k(
    const float* __restrict__ xin, const float* __restrict__ mask,
    const float* __restrict__ b_emb, const float* __restrict__ b_in,
    const float* __restrict__ b1v, const float* __restrict__ bA1,
    const float* __restrict__ WA3, const float* __restrict__ bA3,
    char* __restrict__ ws, float* __restrict__ outp) {
  const int level = blockIdx.x;        // 0 = embed, 1..7 = recurrent
  const int tid   = threadIdx.x;
  const int wave  = tid >> 6;
  const int lane  = tid & 63;
  const int l15   = lane & 15, quad = lane >> 4;

  unsigned* flags = (unsigned*)(ws + OFF_FLAGS);
  const _Float16* WembP = (const _Float16*)(ws + OFF_WEMB);
  const _Float16* Wp    = (const _Float16*)(ws + OFF_W);
  const _Float16* Up    = (const _Float16*)(ws + OFF_U);
  const _Float16* W1p   = (const _Float16*)(ws + OFF_W1);
  const _Float16* WA1p  = (const _Float16*)(ws + OFF_WA1);
  const _Float16* UA1p  = (const _Float16*)(ws + OFF_UA1);

  __shared__ _Float16 xt_sw[32 * 65 * 8];   // xt  [64 x 256] A-frag, padded
  __shared__ _Float16 ht_sw[32 * 65 * 8];   // h_tm1 f16 A-frag
  __shared__ _Float16 hin_sw[64 * 65 * 8];  // G1  [64 x 512] A-frag
  __shared__ float    amat[64 * 68];        // action acts fp32
  __shared__ float    g_both[64], g_xo[64], g_ho[64], g_hv[64];
  __shared__ float    bemb_s[256], bin_s[512], b1_s[256], bA1_s[64], WA3_s[64], bA3_s[1];

  // load constants to LDS once (persist across the whole sequence)
  if (tid < 512) bin_s[tid] = b_in[tid];
  if (tid < 256) { bemb_s[tid] = b_emb[tid]; b1_s[tid] = b1v[tid]; }
  if (tid < 64)  { bA1_s[tid] = bA1[tid]; WA3_s[tid] = WA3[tid]; g_hv[tid] = 0.0f; }
  if (tid == 0)  bA3_s[0] = bA3[0];
  for (int i = tid; i < 32 * 65 * 8; i += 512) ht_sw[i] = (_Float16)0.0f;
  __syncthreads();

  // ---------------- stage 0: embedding ----------------
  if (level == 0) {
    _Float16* hb0 = (_Float16*)(ws + OFF_HBUF);
    unsigned* myf = flags + 0;
    const int sx = tid >> 3, f0 = (tid & 7) * 32;  // staging assignment
    for (int t = 0; t < SS; ++t) {
      // stage x[s, t, f0..f0+31] -> f16 A-frags
      const float* src = xin + ((size_t)sx * SS + t) * DIN + f0;
      #pragma unroll
      for (int c = 0; c < 4; ++c) {
        f32x4 v0 = *(const f32x4*)(src + c * 8);
        f32x4 v1 = *(const f32x4*)(src + c * 8 + 4);
        f16x8 p;
        p[0]=(_Float16)v0[0]; p[1]=(_Float16)v0[1]; p[2]=(_Float16)v0[2]; p[3]=(_Float16)v0[3];
        p[4]=(_Float16)v1[0]; p[5]=(_Float16)v1[1]; p[6]=(_Float16)v1[2]; p[7]=(_Float16)v1[3];
        *(f16x8*)(xt_sw + aoff((tid & 7) * 4 + c, sx)) = p;
      }
      __syncthreads();
      f32x4 acc[2][4] = {};
      #pragma unroll
      for (int kt = 0; kt < 8; ++kt) {
        f16x8 ax[4];
        #pragma unroll
        for (int mt = 0; mt < 4; ++mt)
          ax[mt] = *(const f16x8*)(xt_sw + aoff(kt * 4 + quad, mt * 16 + l15));
        #pragma unroll
        for (int i = 0; i < 2; ++i) {
          int nt = wave * 2 + i;
          f16x8 b = *(const f16x8*)(WembP + (((size_t)(kt * 16 + nt) * 4 + quad) * 16 + l15) * 8);
          #pragma unroll
          for (int mt = 0; mt < 4; ++mt)
            acc[i][mt] = __builtin_amdgcn_mfma_f32_16x16x32_f16(ax[mt], b, acc[i][mt], 0, 0, 0);
        }
      }
      #pragma unroll
      for (int i = 0; i < 2; ++i) {
        int n = (wave * 2 + i) * 16 + l15;
        float be = bemb_s[n];
        #pragma unroll
        for (int mt = 0; mt < 4; ++mt)
          #pragma unroll
          for (int r = 0; r < 4; ++r) {
            int s = mt * 16 + quad * 4 + r;
            gsth(&hb0[((size_t)t * BB + s) * DH + n], (_Float16)(acc[i][mt][r] + be));
          }
      }
      __syncthreads();  // drain stores (vmcnt) before publish
      if (tid == 0)
        __hip_atomic_store(myf, (unsigned)(t + 1), __ATOMIC_RELEASE, __HIP_MEMORY_SCOPE_AGENT);
    }
    return;
  }

  // ---------------- stages 1..7 ----------------
  _Float16* hb_prev = (_Float16*)(ws + OFF_HBUF + (size_t)(level - 1) * SZ_HBUF);
  _Float16* hb_my   = (level < 7) ? (_Float16*)(ws + OFF_HBUF + (size_t)level * SZ_HBUF) : nullptr;
  float* nm_prev = (level >= 2) ? (float*)(ws + OFF_NM + (size_t)(level - 1) * SZ_NM) : nullptr;
  float* hv_prev = (level >= 2) ? (float*)(ws + OFF_HV + (size_t)(level - 1) * SZ_NM) : nullptr;
  float* nm_my   = (level < 7) ? (float*)(ws + OFF_NM + (size_t)level * SZ_NM) : nullptr;
  float* hv_my   = (level < 7) ? (float*)(ws + OFF_HV + (size_t)level * SZ_NM) : nullptr;
  unsigned* pf   = flags + (level - 1) * 16;
  unsigned* myf  = flags + level * 16;

  float hreg[2][4][4] = {};  // fp32 h-state: (nt=wave*2+i, mt, r) x n=..+l15
  unsigned seen = 0;

  for (int t = 0; t < SS; ++t) {
    // 1. wait for producer (h[t]; nm shift needs t+1 for level>=2)
    if (tid == 0) {
      unsigned need = (level == 1) ? (unsigned)(t + 1)
                                   : (unsigned)((t + 2 <= SS) ? (t + 2) : SS);
      if (seen < need) {
        unsigned v = __hip_atomic_load(pf, __ATOMIC_RELAXED, __HIP_MEMORY_SCOPE_AGENT);
        int guard = 0;
        while (v < need && guard < (1 << 22)) {
          __builtin_amdgcn_s_sleep(2);
          v = __hip_atomic_load(pf, __ATOMIC_RELAXED, __HIP_MEMORY_SCOPE_AGENT);
          ++guard;
        }
        seen = v;
      }
    }
    __syncthreads();

    // 2. copy producer h[t] (f16, [s][k] row-major) -> xt A-frags in LDS
    {
      const _Float16* hsrc = hb_prev + (size_t)t * BB * DH;
      #pragma unroll
      for (int c = 0; c < 4; ++c) {
        int unit = tid + 512 * c;           // 2048 frags total
        int s = unit >> 5, kg = unit & 31;  // 32 consecutive lanes: contiguous 16B
        const _Float16* p = hsrc + s * DH + kg * 8;
        unsigned long long lo = gld64(p), hi = gld64(p + 4);
        unsigned long long* d = (unsigned long long*)(xt_sw + aoff(kg, s));
        d[0] = lo; d[1] = hi;
      }
    }
    __syncthreads();

    // 3. action matmul: a = lrelu(xt@WA1 + h@UA1 + bA1) -> amat [64 x 64]
    {
      const int mt = wave & 3, ntb = wave >> 2;  // nts {ntb, ntb+2}
      f32x4 aacc[2] = {};
      #pragma unroll
      for (int kt = 0; kt < 8; ++kt) {
        f16x8 a = *(const f16x8*)(xt_sw + aoff(kt * 4 + quad, mt * 16 + l15));
        #pragma unroll
        for (int i = 0; i < 2; ++i) {
          int nt = ntb + i * 2;
          f16x8 b = *(const f16x8*)(WA1p + (((size_t)(kt * 4 + nt) * 4 + quad) * 16 + l15) * 8);
          aacc[i] = __builtin_amdgcn_mfma_f32_16x16x32_f16(a, b, aacc[i], 0, 0, 0);
        }
      }
      #pragma unroll
      for (int kt = 0; kt < 8; ++kt) {
        f16x8 a = *(const f16x8*)(ht_sw + aoff(kt * 4 + quad, mt * 16 + l15));
        #pragma unroll
        for (int i = 0; i < 2; ++i) {
          int nt = ntb + i * 2;
          f16x8 b = *(const f16x8*)(UA1p + (((size_t)(kt * 4 + nt) * 4 + quad) * 16 + l15) * 8);
          aacc[i] = __builtin_amdgcn_mfma_f32_16x16x32_f16(a, b, aacc[i], 0, 0, 0);
        }
      }
      #pragma unroll
      for (int i = 0; i < 2; ++i) {
        int c = (ntb + i * 2) * 16 + l15;
        float ba = bA1_s[c];
        #pragma unroll
        for (int r = 0; r < 4; ++r)
          amat[(mt * 16 + quad * 4 + r) * 68 + c] = lrelu(aacc[i][r] + ba);
      }
    }
    __syncthreads();

    // 4. gating (wave 0 only; overlaps with phase 5 on waves 1..7)
    if (tid < 64) {
      int s = tid;
      float z = bA3_s[0];
      #pragma unroll
      for (int c4 = 0; c4 < 16; ++c4) {
        f32x4 av = *(const f32x4*)(amat + s * 68 + c4 * 4);
        f32x4 wv = *(const f32x4*)(WA3_s + c4 * 4);
        z += av[0] * wv[0] + av[1] * wv[1] + av[2] * wv[2] + av[3] * wv[3];
      }
      float nm0 = fminf(fmaxf(0.2f * z + 0.5f, 0.0f), 1.0f);
      float pm, phv;
      if (level == 1) {
        float mv = mask[(size_t)s * SS + t];
        pm = mv; phv = mv;
      } else {
        pm  = (t + 1 < SS) ? gldf(&nm_prev[(size_t)(t + 1) * BB + s]) : 1.0f;
        phv = gldf(&hv_prev[(size_t)t * BB + s]);
      }
      float lv   = (t == SS - 1) ? 1.0f : 0.0f;
      float nm   = (1.0f - lv) * (pm * phv * nm0);
      float hvp  = g_hv[s];
      float omn  = 1.0f - nm;
      float both = pm * phv * omn * hvp;
      float xo   = pm * phv * (nm + omn * (1.0f - hvp));
      float ho   = (1.0f - pm * phv) * omn * hvp;
      float hv   = both + xo + ho;
      g_both[s] = both; g_xo[s] = xo; g_ho[s] = ho; g_hv[s] = hv;
      if (level < 7) {
        gstf(&nm_my[(size_t)t * BB + s], nm);
        gstf(&hv_my[(size_t)t * BB + s], hv);
      }
    }

    // 5. G1 = lrelu(xt@W + h@U + b) -> hin_sw [64 x 512] A-frags
    {
      f32x4 acc[4][4] = {};  // [i(nt)][mt]
      #pragma unroll
      for (int kt = 0; kt < 8; ++kt) {
        f16x8 ax[4];
        #pragma unroll
        for (int mt = 0; mt < 4; ++mt)
          ax[mt] = *(const f16x8*)(xt_sw + aoff(kt * 4 + quad, mt * 16 + l15));
        #pragma unroll
        for (int i = 0; i < 4; ++i) {
          int nt = wave * 4 + i;
          f16x8 b = *(const f16x8*)(Wp + (((size_t)(kt * 32 + nt) * 4 + quad) * 16 + l15) * 8);
          #pragma unroll
          for (int mt = 0; mt < 4; ++mt)
            acc[i][mt] = __builtin_amdgcn_mfma_f32_16x16x32_f16(ax[mt], b, acc[i][mt], 0, 0, 0);
        }
      }
      #pragma unroll
      for (int kt = 0; kt < 8; ++kt) {
        f16x8 ah[4];
        #pragma unroll
        for (int mt = 0; mt < 4; ++mt)
          ah[mt] = *(const f16x8*)(ht_sw + aoff(kt * 4 + quad, mt * 16 + l15));
        #pragma unroll
        for (int i = 0; i < 4; ++i) {
          int nt = wave * 4 + i;
          f16x8 b = *(const f16x8*)(Up + (((size_t)(kt * 32 + nt) * 4 + quad) * 16 + l15) * 8);
          #pragma unroll
          for (int mt = 0; mt < 4; ++mt)
            acc[i][mt] = __builtin_amdgcn_mfma_f32_16x16x32_f16(ah[mt], b, acc[i][mt], 0, 0, 0);
        }
      }
      #pragma unroll
      for (int i = 0; i < 4; ++i) {
        int n = (wave * 4 + i) * 16 + l15;
        int kq = n >> 3, j = n & 7;
        float bv = bin_s[n];
        #pragma unroll
        for (int mt = 0; mt < 4; ++mt)
          #pragma unroll
          for (int r = 0; r < 4; ++r)
            hin_sw[aoff(kq, mt * 16 + quad * 4 + r) + j] = (_Float16)lrelu(acc[i][mt][r] + bv);
      }
    }
    __syncthreads();

    // 6. h1 = lrelu(G1@W1 + b1); h = both*h1 + xo*xt + ho*h_tm1
    {
      f32x4 c1[2][4] = {};
      #pragma unroll
      for (int kt = 0; kt < 16; ++kt) {
        f16x8 ah[4];
        #pragma unroll
        for (int mt = 0; mt < 4; ++mt)
          ah[mt] = *(const f16x8*)(hin_sw + aoff(kt * 4 + quad, mt * 16 + l15));
        #pragma unroll
        for (int i = 0; i < 2; ++i) {
          int nt = wave * 2 + i;
          f16x8 b = *(const f16x8*)(W1p + (((size_t)(kt * 16 + nt) * 4 + quad) * 16 + l15) * 8);
          #pragma unroll
          for (int mt = 0; mt < 4; ++mt)
            c1[i][mt] = __builtin_amdgcn_mfma_f32_16x16x32_f16(ah[mt], b, c1[i][mt], 0, 0, 0);
        }
      }
      #pragma unroll
      for (int i = 0; i < 2; ++i) {
        int n = (wave * 2 + i) * 16 + l15;
        int kq = n >> 3, j = n & 7;
        float bv = b1_s[n];
        #pragma unroll
        for (int mt = 0; mt < 4; ++mt)
          #pragma unroll
          for (int r = 0; r < 4; ++r) {
            int s = mt * 16 + quad * 4 + r;
            float h1  = lrelu(c1[i][mt][r] + bv);
            float xtv = (float)xt_sw[aoff(kq, s) + j];
            float hn  = g_both[s] * h1 + g_xo[s] * xtv + g_ho[s] * hreg[i][mt][r];
            hreg[i][mt][r] = hn;
            ht_sw[aoff(kq, s) + j] = (_Float16)hn;
            if (level < 7)
              gsth(&hb_my[((size_t)t * BB + s) * DH + n], (_Float16)hn);
            else if (t == SS - 1)
              outp[(size_t)s * DH + n] = hn;
          }
      }
    }
    __syncthreads();  // drain exchange stores before publish
    if (level < 7 && tid == 0)
      __hip_atomic_store(myf, (unsigned)(t + 1), __ATOMIC_RELEASE, __HIP_MEMORY_SCOPE_AGENT);
  }
}

// ---------------------------------------------------------------------------
extern "C" void kernel_launch(void* const* d_in, const int* in_sizes, int n_in,
                              void* d_out, int out_size, void* d_ws, size_t ws_size,
                              hipStream_t stream) {
  const float* x     = (const float*)d_in[0];
  const float* mask  = (const float*)d_in[1];
  const float* W_emb = (const float*)d_in[3];
  const float* b_emb = (const float*)d_in[4];
  const float* W     = (const float*)d_in[5];
  const float* U     = (const float*)d_in[6];
  const float* b     = (const float*)d_in[7];
  const float* W1    = (const float*)d_in[8];
  const float* b1    = (const float*)d_in[9];
  const float* WA1   = (const float*)d_in[10];
  const float* UA1   = (const float*)d_in[11];
  const float* bA1   = (const float*)d_in[12];
  const float* WA3   = (const float*)d_in[13];
  const float* bA3   = (const float*)d_in[14];
  char* ws = (char*)d_ws;

  if (ws_size < WS_NEEDED) return;

  zero_flags_k<<<1, 1024, 0, stream>>>((unsigned*)(ws + OFF_FLAGS));
  pack_weight_k<<<(DIN * DH + 255) / 256, 256, 0, stream>>>(W_emb, (_Float16*)(ws + OFF_WEMB), DIN, DH);
  pack_weight_k<<<(DH * DINNER + 255) / 256, 256, 0, stream>>>(W, (_Float16*)(ws + OFF_W), DH, DINNER);
  pack_weight_k<<<(DH * DINNER + 255) / 256, 256, 0, stream>>>(U, (_Float16*)(ws + OFF_U), DH, DINNER);
  pack_weight_k<<<(DINNER * DH + 255) / 256, 256, 0, stream>>>(W1, (_Float16*)(ws + OFF_W1), DINNER, DH);
  pack_weight_k<<<(DH * DA + 255) / 256, 256, 0, stream>>>(WA1, (_Float16*)(ws + OFF_WA1), DH, DA);
  pack_weight_k<<<(DH * DA + 255) / 256, 256, 0, stream>>>(UA1, (_Float16*)(ws + OFF_UA1), DH, DA);

  pipeline_k<<<8, 512, 0, stream>>>(x, mask, b_emb, b, b1, bA1, WA3, bA3,
                                    ws, (float*)d_out);
}

// Round 3
// 3876.986 us; speedup vs baseline: 3.1053x; 3.1053x over previous
//
#include <hip/hip_runtime.h>
#include <stdint.h>

// ---------------------------------------------------------------------------
// Encoder_Processor round 3: tensor-parallel pipeline.
// emb_k: 64 WGs compute xe = x@W_emb + b_emb (t-split), f16 row-major.
// pipe_k: 7 levels x 8 WGs. Each WG holds its weight chunk in REGISTERS
// (W/U cols j*64.., W1 cols j*32.., 128 VGPRs) + action frags in LDS.
// Per step: stage xt/h from L3 -> G1 chunk MFMA -> broadcast G1 (L3) ->
// W1 MFMA + gates + combine -> broadcast h chunk. Sync = per-WG release
// flags, 8-load min poll. All exchange via agent-scope atomics (L3).
// ---------------------------------------------------------------------------

typedef _Float16 f16x8 __attribute__((ext_vector_type(8)));
typedef float    f32x4 __attribute__((ext_vector_type(4)));

static constexpr int SS = 256, BB = 64, DIN = 256, DH = 256, DNN = 512, DA = 64;

// workspace layout (bytes)
static constexpr size_t OFF_FLAGS = 0;                    // u32[2048] = 8KB
static constexpr size_t OFF_WEMB  = 8192;
static constexpr size_t SZ_WEMB   = (size_t)DIN * DH * 2;
static constexpr size_t OFF_W     = OFF_WEMB + SZ_WEMB;
static constexpr size_t SZ_WU     = (size_t)DH * DNN * 2;
static constexpr size_t OFF_U     = OFF_W + SZ_WU;
static constexpr size_t OFF_W1    = OFF_U + SZ_WU;
static constexpr size_t SZ_W1     = (size_t)DNN * DH * 2;
static constexpr size_t OFF_WA1   = OFF_W1 + SZ_W1;
static constexpr size_t SZ_WA     = (size_t)DH * DA * 2;
static constexpr size_t OFF_UA1   = OFF_WA1 + SZ_WA;
static constexpr size_t OFF_NM    = OFF_UA1 + SZ_WA;      // 8 x 64KB
static constexpr size_t SZ_NM     = (size_t)SS * BB * 4;
static constexpr size_t OFF_HV    = OFF_NM + 8 * SZ_NM;
static constexpr size_t OFF_G1    = OFF_HV + 8 * SZ_NM;   // 8 x 64KB
static constexpr size_t SZ_G1     = (size_t)BB * DNN * 2;
static constexpr size_t OFF_Z     = OFF_G1 + 8 * SZ_G1;   // 8 x 4KB
static constexpr size_t OFF_HB    = (size_t)4 << 20;      // 8 x 8MB (f16 [t][s][n])
static constexpr size_t SZ_HB     = (size_t)SS * BB * DH * 2;
static constexpr size_t WS_NEEDED = OFF_HB + 8 * SZ_HB;   // ~68MB

__device__ __forceinline__ float lrelu(float v) { return v >= 0.0f ? v : 0.01f * v; }

// agent-scope data plane (coherence point = L3; L2 weight residency untouched)
__device__ __forceinline__ float gldf(const float* p) {
  return __hip_atomic_load((float*)p, __ATOMIC_RELAXED, __HIP_MEMORY_SCOPE_AGENT);
}
__device__ __forceinline__ void gstf(float* p, float v) {
  __hip_atomic_store(p, v, __ATOMIC_RELAXED, __HIP_MEMORY_SCOPE_AGENT);
}
__device__ __forceinline__ void gsth(_Float16* p, _Float16 v) {
  __hip_atomic_store(p, v, __ATOMIC_RELAXED, __HIP_MEMORY_SCOPE_AGENT);
}
__device__ __forceinline__ unsigned long long gld64(const _Float16* p) {
  return __hip_atomic_load((const unsigned long long*)p, __ATOMIC_RELAXED,
                           __HIP_MEMORY_SCOPE_AGENT);
}

// poll until min over 8 consecutive u32 flags >= need (bounded guard)
__device__ __forceinline__ void poll8(unsigned* base, unsigned need) {
  for (int g = 0; g < (1 << 18); ++g) {
    unsigned mn = ~0u;
    #pragma unroll
    for (int p = 0; p < 8; ++p) {
      unsigned v = __hip_atomic_load(base + p, __ATOMIC_RELAXED, __HIP_MEMORY_SCOPE_AGENT);
      mn = v < mn ? v : mn;
    }
    if (mn >= need) return;
    __builtin_amdgcn_s_sleep(1);
  }
}

// ---------------------------------------------------------------------------
__global__ void zero_flags_k(unsigned* f) {
  f[threadIdx.x] = 0u;
  f[threadIdx.x + 1024] = 0u;
}

// pack fp32 row-major [K][N] into f16 MFMA B-frag order:
// addr = (((kt*(N/16)+nt)*4+q)*16+l)*8 + j ; k = kt*32+q*8+j, n = nt*16+l
__global__ void pack_weight_k(const float* __restrict__ src, _Float16* __restrict__ dst,
                              int K, int N) {
  int idx = blockIdx.x * 256 + threadIdx.x;
  if (idx >= K * N) return;
  int k = idx / N, n = idx - k * N;
  int kt = k >> 5, q = (k >> 3) & 3, jj = k & 7;
  int nt = n >> 4, l = n & 15;
  size_t p = (((size_t)(kt * (N >> 4) + nt) * 4 + q) * 16 + l) * 8 + jj;
  dst[p] = (_Float16)src[idx];
}

// ---------------------------------------------------------------------------
// embedding: 64 WGs x 512 thr, WG e handles t in {e, e+64, e+128, e+192}
// ---------------------------------------------------------------------------
__global__ __launch_bounds__(512, 2) void emb_k(const float* __restrict__ xin,
                                                const float* __restrict__ b_emb,
                                                char* __restrict__ ws) {
  const int tid = threadIdx.x, wave = tid >> 6, lane = tid & 63;
  const int l15 = lane & 15, quad = lane >> 4;
  const _Float16* Wp = (const _Float16*)(ws + OFF_WEMB);
  _Float16* xe = (_Float16*)(ws + OFF_HB);  // level-0 h buffer

  f16x8 bE[16];
  #pragma unroll
  for (int kt = 0; kt < 8; ++kt)
    #pragma unroll
    for (int i = 0; i < 2; ++i)
      bE[kt * 2 + i] = *(const f16x8*)(Wp + (((size_t)(kt * 16 + (wave * 2 + i)) * 4 + quad) * 16 + l15) * 8);
  float ber[2] = { b_emb[(wave * 2) * 16 + l15], b_emb[(wave * 2 + 1) * 16 + l15] };

  __shared__ _Float16 xtF[32 * 65 * 8];

  for (int tt = 0; tt < 4; ++tt) {
    const int t = (int)blockIdx.x + 64 * tt;
    // stage x[s][t][:] fp32 -> f16 A-frags
    #pragma unroll
    for (int c = 0; c < 4; ++c) {
      int u = tid + 512 * c;            // 2048 units of 8 floats
      int s = u >> 5, kg = u & 31;
      const float* src = xin + ((size_t)s * SS + t) * DIN + kg * 8;
      f32x4 v0 = *(const f32x4*)src, v1 = *(const f32x4*)(src + 4);
      f16x8 p;
      p[0]=(_Float16)v0[0]; p[1]=(_Float16)v0[1]; p[2]=(_Float16)v0[2]; p[3]=(_Float16)v0[3];
      p[4]=(_Float16)v1[0]; p[5]=(_Float16)v1[1]; p[6]=(_Float16)v1[2]; p[7]=(_Float16)v1[3];
      *(f16x8*)(xtF + ((size_t)kg * 65 + s) * 8) = p;
    }
    __syncthreads();
    f32x4 acc[2][4] = {};
    #pragma unroll
    for (int kt = 0; kt < 8; ++kt) {
      f16x8 ax[4];
      #pragma unroll
      for (int mt = 0; mt < 4; ++mt)
        ax[mt] = *(const f16x8*)(xtF + (((size_t)(kt * 4 + quad)) * 65 + (mt * 16 + l15)) * 8);
      #pragma unroll
      for (int i = 0; i < 2; ++i)
        #pragma unroll
        for (int mt = 0; mt < 4; ++mt)
          acc[i][mt] = __builtin_amdgcn_mfma_f32_16x16x32_f16(ax[mt], bE[kt * 2 + i], acc[i][mt], 0, 0, 0);
    }
    #pragma unroll
    for (int i = 0; i < 2; ++i) {
      int n = (wave * 2 + i) * 16 + l15;
      #pragma unroll
      for (int mt = 0; mt < 4; ++mt)
        #pragma unroll
        for (int r = 0; r < 4; ++r) {
          int s = mt * 16 + quad * 4 + r;
          gsth(&xe[((size_t)t * BB + s) * DH + n], (_Float16)(acc[i][mt][r] + ber[i]));
        }
    }
    __syncthreads();
  }
}

// ---------------------------------------------------------------------------
// pipeline: 56 WGs (7 levels x 8 shards) x 512 thr
// ---------------------------------------------------------------------------
__global__ __launch_bounds__(512, 2) void pipe_k(
    const float* __restrict__ mask, const float* __restrict__ b_in,
    const float* __restrict__ b1v, const float* __restrict__ bA1,
    const float* __restrict__ WA3, const float* __restrict__ bA3,
    char* __restrict__ ws, float* __restrict__ outp) {
  const int level = 1 + ((int)blockIdx.x >> 3);
  const int j     = (int)blockIdx.x & 7;
  const int tid   = threadIdx.x, wave = tid >> 6, lane = tid & 63;
  const int l15   = lane & 15, quad = lane >> 4;

  unsigned* flags = (unsigned*)(ws + OFF_FLAGS);
  unsigned* hfl   = flags + level * 64;             // own-level h flags [8]
  unsigned* hflP  = flags + (level - 1) * 64;       // prev-level h flags
  unsigned* gfl   = flags + (8 + level) * 64;       // own-level G1 flags

  const _Float16* Wp   = (const _Float16*)(ws + OFF_W);
  const _Float16* Up   = (const _Float16*)(ws + OFF_U);
  const _Float16* W1p  = (const _Float16*)(ws + OFF_W1);
  const _Float16* WA1p = (const _Float16*)(ws + OFF_WA1);
  const _Float16* UA1p = (const _Float16*)(ws + OFF_UA1);

  const _Float16* xsrc = (const _Float16*)(ws + OFF_HB) + (size_t)(level - 1) * SS * BB * DH;
  _Float16*       hdst = (_Float16*)(ws + OFF_HB) + (size_t)level * SS * BB * DH;
  _Float16*       g1b  = (_Float16*)(ws + OFF_G1 + (size_t)level * SZ_G1);
  float*          zb   = (float*)(ws + OFF_Z + (size_t)level * 4096);
  float*          nmW  = (float*)(ws + OFF_NM + (size_t)level * SZ_NM);
  float*          hvW  = (float*)(ws + OFF_HV + (size_t)level * SZ_NM);
  const float*    nmR  = (const float*)(ws + OFF_NM + (size_t)(level - 1) * SZ_NM);
  const float*    hvR  = (const float*)(ws + OFF_HV + (size_t)(level - 1) * SZ_NM);

  // --- weight chunks in registers (loaded once; L2-resident source) ---
  const int ntG = j * 4 + (wave >> 1);   // W/U n-tile (global, of 32)
  const int m0  = (wave & 1) * 2;        // G1 m-tile pair {m0, m0+1}
  f16x8 bW[8], bU[8];
  #pragma unroll
  for (int kt = 0; kt < 8; ++kt) {
    bW[kt] = *(const f16x8*)(Wp + (((size_t)(kt * 32 + ntG) * 4 + quad) * 16 + l15) * 8);
    bU[kt] = *(const f16x8*)(Up + (((size_t)(kt * 32 + ntG) * 4 + quad) * 16 + l15) * 8);
  }
  const int nt1 = j * 2 + (wave & 1);    // W1 n-tile (global, of 16)
  const int mt1 = wave >> 1;             // W1/combine m-tile
  f16x8 b1f[16];
  #pragma unroll
  for (int kt = 0; kt < 16; ++kt)
    b1f[kt] = *(const f16x8*)(W1p + (((size_t)(kt * 16 + nt1) * 4 + quad) * 16 + l15) * 8);

  const int nG = ntG * 16 + l15;         // G1 output col (global)
  const int nC = nt1 * 16 + l15;         // combine col (global, 0..255)
  const float bir = b_in[nG];
  const float b1r = b1v[nC];
  const float wa3r = WA3[(j & 3) * 16 + l15];
  const float ba1r = bA1[(j & 3) * 16 + l15];
  const float bA3v = bA3[0];

  // --- LDS ---
  __shared__ _Float16 xtF[32 * 65 * 8];   // xt A-frags  [kq<32][s<64]
  __shared__ _Float16 htF[32 * 65 * 8];   // h_tm1 A-frags
  __shared__ _Float16 g1F[64 * 65 * 8];   // G1 A-frags  [kq<64][s<64]
  __shared__ _Float16 waF[16 * 64 * 8];   // action b-frags (WGs 0-3)
  __shared__ float gB[64], gX[64], gH[64], gHv[64];

  if (j < 4) {
    for (int u = tid; u < 1024; u += 512) {
      int ktm = u >> 6, lu = u & 63, kt = ktm >> 1, m = ktm & 1;
      const _Float16* sp = (m ? UA1p : WA1p) +
          (((size_t)(kt * 4 + j) * 4 + (lu >> 4)) * 16 + (lu & 15)) * 8;
      *(f16x8*)(waF + (size_t)u * 8) = *(const f16x8*)sp;
    }
  }
  for (int i = tid; i < 32 * 65 * 8; i += 512) htF[i] = (_Float16)0;
  if (tid < 64) gHv[tid] = 0.0f;
  float hreg[4] = {0.f, 0.f, 0.f, 0.f};
  __syncthreads();

  for (int t = 0; t < SS; ++t) {
    // -- A: wait producers --
    if (tid == 0) {
      if (t > 0) poll8(hfl, (unsigned)t);                       // own h[t-1]
      if (level >= 2) {                                         // xt[t] + nm[t+1]
        unsigned need = (unsigned)((t + 2 <= SS) ? (t + 2) : SS);
        poll8(hflP, need);
      }
    }
    __syncthreads();

    // -- B: stage xt (and h_tm1) from L3 into A-frag LDS --
    {
      const _Float16* xp = xsrc + (size_t)t * BB * DH;
      #pragma unroll
      for (int c = 0; c < 4; ++c) {
        int u = tid + 512 * c, s = u >> 5, kq = u & 31;
        const _Float16* p = xp + s * DH + kq * 8;
        unsigned long long lo = gld64(p), hi = gld64(p + 4);
        unsigned long long* d = (unsigned long long*)(xtF + ((size_t)kq * 65 + s) * 8);
        d[0] = lo; d[1] = hi;
      }
      if (t > 0) {
        const _Float16* hp = hdst + (size_t)(t - 1) * BB * DH;
        #pragma unroll
        for (int c = 0; c < 4; ++c) {
          int u = tid + 512 * c, s = u >> 5, kq = u & 31;
          const _Float16* p = hp + s * DH + kq * 8;
          unsigned long long lo = gld64(p), hi = gld64(p + 4);
          unsigned long long* d = (unsigned long long*)(htF + ((size_t)kq * 65 + s) * 8);
          d[0] = lo; d[1] = hi;
        }
      }
    }
    __syncthreads();

    // -- C: G1 chunk MFMA (weights in registers) + write + action --
    {
      f32x4 a0 = {}, a1 = {};
      #pragma unroll
      for (int kt = 0; kt < 8; ++kt) {
        int kq = kt * 4 + quad;
        f16x8 ax0 = *(const f16x8*)(xtF + ((size_t)kq * 65 + (m0 * 16 + l15)) * 8);
        f16x8 ax1 = *(const f16x8*)(xtF + ((size_t)kq * 65 + ((m0 + 1) * 16 + l15)) * 8);
        f16x8 ah0 = *(const f16x8*)(htF + ((size_t)kq * 65 + (m0 * 16 + l15)) * 8);
        f16x8 ah1 = *(const f16x8*)(htF + ((size_t)kq * 65 + ((m0 + 1) * 16 + l15)) * 8);
        a0 = __builtin_amdgcn_mfma_f32_16x16x32_f16(ax0, bW[kt], a0, 0, 0, 0);
        a1 = __builtin_amdgcn_mfma_f32_16x16x32_f16(ax1, bW[kt], a1, 0, 0, 0);
        a0 = __builtin_amdgcn_mfma_f32_16x16x32_f16(ah0, bU[kt], a0, 0, 0, 0);
        a1 = __builtin_amdgcn_mfma_f32_16x16x32_f16(ah1, bU[kt], a1, 0, 0, 0);
      }
      #pragma unroll
      for (int r = 0; r < 4; ++r) {
        gsth(&g1b[(size_t)(m0 * 16 + quad * 4 + r) * DNN + nG], (_Float16)lrelu(a0[r] + bir));
        gsth(&g1b[(size_t)((m0 + 1) * 16 + quad * 4 + r) * DNN + nG], (_Float16)lrelu(a1[r] + bir));
      }
    }
    if (j < 4 && wave < 4) {  // action shard: a[:, j*16..] and z partial
      f32x4 aa = {};
      #pragma unroll
      for (int kt = 0; kt < 8; ++kt) {
        int kq = kt * 4 + quad;
        f16x8 ax = *(const f16x8*)(xtF + ((size_t)kq * 65 + (wave * 16 + l15)) * 8);
        f16x8 ah = *(const f16x8*)(htF + ((size_t)kq * 65 + (wave * 16 + l15)) * 8);
        f16x8 bWa = *(const f16x8*)(waF + ((size_t)(kt * 2) * 64 + lane) * 8);
        f16x8 bUa = *(const f16x8*)(waF + ((size_t)(kt * 2 + 1) * 64 + lane) * 8);
        aa = __builtin_amdgcn_mfma_f32_16x16x32_f16(ax, bWa, aa, 0, 0, 0);
        aa = __builtin_amdgcn_mfma_f32_16x16x32_f16(ah, bUa, aa, 0, 0, 0);
      }
      #pragma unroll
      for (int r = 0; r < 4; ++r) {
        float v = lrelu(aa[r] + ba1r) * wa3r;
        v += __shfl_xor(v, 1); v += __shfl_xor(v, 2);
        v += __shfl_xor(v, 4); v += __shfl_xor(v, 8);
        if (l15 == 0) gstf(&zb[j * 64 + wave * 16 + quad * 4 + r], v);
      }
    }
    __syncthreads();  // drain G1/z stores
    if (tid == 0)
      __hip_atomic_store(gfl + j, (unsigned)(t + 1), __ATOMIC_RELEASE, __HIP_MEMORY_SCOPE_AGENT);

    // -- E: wait all 8 G1 shards --
    if (tid == 0) poll8(gfl, (unsigned)(t + 1));
    __syncthreads();

    // -- F: stage full G1 -> LDS A-frags; gates on tid<64 --
    #pragma unroll
    for (int c = 0; c < 8; ++c) {
      int u = tid + 512 * c, s = u >> 6, kq = u & 63;
      const _Float16* p = g1b + (size_t)s * DNN + kq * 8;
      unsigned long long lo = gld64(p), hi = gld64(p + 4);
      unsigned long long* d = (unsigned long long*)(g1F + ((size_t)kq * 65 + s) * 8);
      d[0] = lo; d[1] = hi;
    }
    if (tid < 64) {
      int s = tid;
      float z = bA3v + gldf(&zb[s]) + gldf(&zb[64 + s]) + gldf(&zb[128 + s]) + gldf(&zb[192 + s]);
      float nm0 = fminf(fmaxf(0.2f * z + 0.5f, 0.0f), 1.0f);
      float pm, phv;
      if (level == 1) {
        float mv = mask[(size_t)s * SS + t];
        pm = mv; phv = mv;
      } else {
        pm  = (t + 1 < SS) ? gldf(&nmR[(size_t)(t + 1) * BB + s]) : 1.0f;
        phv = gldf(&hvR[(size_t)t * BB + s]);
      }
      float lv   = (t == SS - 1) ? 1.0f : 0.0f;
      float nm   = (1.0f - lv) * (pm * phv * nm0);
      float hvp  = gHv[s], omn = 1.0f - nm;
      float both = pm * phv * omn * hvp;
      float xo   = pm * phv * (nm + omn * (1.0f - hvp));
      float ho   = (1.0f - pm * phv) * omn * hvp;
      float hv   = both + xo + ho;
      gB[s] = both; gX[s] = xo; gH[s] = ho; gHv[s] = hv;
      if (j == 0 && level < 7) {
        gstf(&nmW[(size_t)t * BB + s], nm);
        gstf(&hvW[(size_t)t * BB + s], hv);
      }
    }
    __syncthreads();

    // -- G: h1 = lrelu(G1@W1+b1); combine; write h chunk --
    {
      f32x4 c1 = {};
      #pragma unroll
      for (int kt = 0; kt < 16; ++kt) {
        f16x8 ag = *(const f16x8*)(g1F + ((size_t)(kt * 4 + quad) * 65 + (mt1 * 16 + l15)) * 8);
        c1 = __builtin_amdgcn_mfma_f32_16x16x32_f16(ag, b1f[kt], c1, 0, 0, 0);
      }
      const int kqc = nC >> 3, sub = nC & 7;
      #pragma unroll
      for (int r = 0; r < 4; ++r) {
        int s = mt1 * 16 + quad * 4 + r;
        float h1  = lrelu(c1[r] + b1r);
        float xtv = (float)xtF[((size_t)kqc * 65 + s) * 8 + sub];
        float hn  = gB[s] * h1 + gX[s] * xtv + gH[s] * hreg[r];
        hreg[r] = hn;
        gsth(&hdst[((size_t)t * BB + s) * DH + nC], (_Float16)hn);
        if (level == 7 && t == SS - 1) outp[(size_t)s * DH + nC] = hn;
      }
    }
    __syncthreads();  // drain h stores
    if (tid == 0)
      __hip_atomic_store(hfl + j, (unsigned)(t + 1), __ATOMIC_RELEASE, __HIP_MEMORY_SCOPE_AGENT);
  }
}

// ---------------------------------------------------------------------------
extern "C" void kernel_launch(void* const* d_in, const int* in_sizes, int n_in,
                              void* d_out, int out_size, void* d_ws, size_t ws_size,
                              hipStream_t stream) {
  const float* x     = (const float*)d_in[0];
  const float* mask  = (const float*)d_in[1];
  const float* W_emb = (const float*)d_in[3];
  const float* b_emb = (const float*)d_in[4];
  const float* W     = (const float*)d_in[5];
  const float* U     = (const float*)d_in[6];
  const float* b     = (const float*)d_in[7];
  const float* W1    = (const float*)d_in[8];
  const float* b1    = (const float*)d_in[9];
  const float* WA1   = (const float*)d_in[10];
  const float* UA1   = (const float*)d_in[11];
  const float* bA1   = (const float*)d_in[12];
  const float* WA3   = (const float*)d_in[13];
  const float* bA3   = (const float*)d_in[14];
  char* ws = (char*)d_ws;

  if (ws_size < WS_NEEDED) return;

  zero_flags_k<<<1, 1024, 0, stream>>>((unsigned*)(ws + OFF_FLAGS));
  pack_weight_k<<<(DIN * DH + 255) / 256, 256, 0, stream>>>(W_emb, (_Float16*)(ws + OFF_WEMB), DIN, DH);
  pack_weight_k<<<(DH * DNN + 255) / 256, 256, 0, stream>>>(W, (_Float16*)(ws + OFF_W), DH, DNN);
  pack_weight_k<<<(DH * DNN + 255) / 256, 256, 0, stream>>>(U, (_Float16*)(ws + OFF_U), DH, DNN);
  pack_weight_k<<<(DNN * DH + 255) / 256, 256, 0, stream>>>(W1, (_Float16*)(ws + OFF_W1), DNN, DH);
  pack_weight_k<<<(DH * DA + 255) / 256, 256, 0, stream>>>(WA1, (_Float16*)(ws + OFF_WA1), DH, DA);
  pack_weight_k<<<(DH * DA + 255) / 256, 256, 0, stream>>>(UA1, (_Float16*)(ws + OFF_UA1), DH, DA);

  emb_k<<<64, 512, 0, stream>>>(x, b_emb, ws);
  pipe_k<<<56, 512, 0, stream>>>(mask, b, b1, bA1, WA3, bA3, ws, (float*)d_out);
}

// Round 4
// 3598.213 us; speedup vs baseline: 3.3459x; 1.0775x over previous
//
#include <hip/hip_runtime.h>
#include <stdint.h>

// ---------------------------------------------------------------------------
// Encoder_Processor round 4: tensor-parallel pipeline, latency-optimized.
// 7 levels x 8 shards (56 WGs x 512 thr), weights in registers. All global
// exchange is MFMA-frag-linear f16, moved with 16B sc0/sc1 asm ops. Per-wave
// producer polling + chunk streaming; xt[t+1] register prefetch.
// ---------------------------------------------------------------------------

typedef _Float16 f16x8 __attribute__((ext_vector_type(8)));
typedef float    f32x4 __attribute__((ext_vector_type(4)));

static constexpr int SS = 256, BB = 64, DIN = 256, DH = 256, DNN = 512, DA = 64;

// workspace layout (bytes)
static constexpr size_t OFF_FLAGS = 0;                     // u32[2048]
static constexpr size_t OFF_WEMB  = 8192;
static constexpr size_t SZ_WEMB   = (size_t)DIN * DH * 2;
static constexpr size_t OFF_W     = OFF_WEMB + SZ_WEMB;
static constexpr size_t SZ_WU     = (size_t)DH * DNN * 2;
static constexpr size_t OFF_U     = OFF_W + SZ_WU;
static constexpr size_t OFF_W1    = OFF_U + SZ_WU;
static constexpr size_t SZ_W1     = (size_t)DNN * DH * 2;
static constexpr size_t OFF_WA1   = OFF_W1 + SZ_W1;
static constexpr size_t SZ_WA     = (size_t)DH * DA * 2;
static constexpr size_t OFF_UA1   = OFF_WA1 + SZ_WA;
static constexpr size_t OFF_NM    = OFF_UA1 + SZ_WA;       // 8 x 64KB fp32 [t][s]
static constexpr size_t SZ_NM     = (size_t)SS * BB * 4;
static constexpr size_t OFF_HV    = OFF_NM + 8 * SZ_NM;
static constexpr size_t OFF_G1    = OFF_HV + 8 * SZ_NM;    // 8 x 64KB f16 frag [kq<64][s<64]
static constexpr size_t SZ_G1     = (size_t)BB * DNN * 2;
static constexpr size_t OFF_Z     = OFF_G1 + 8 * SZ_G1;    // 8 x 4KB fp32
static constexpr size_t OFF_HB    = (size_t)4 << 20;       // 8 x 8MB f16 frag [t][kq<32][s<64]
static constexpr size_t SZ_HB     = (size_t)SS * BB * DH * 2;
static constexpr size_t WS_NEEDED = OFF_HB + 8 * SZ_HB;

__device__ __forceinline__ float lrelu(float v) { return v >= 0.0f ? v : 0.01f * v; }

// --- 16B / 4B coherent (L1+L2 bypass, L3 coherence point) asm ops ----------
// Loads: value NOT valid until vwait()! Callers batch issues then vwait once.
__device__ __forceinline__ f32x4 ld128(const f32x4* p) {
  f32x4 r;
  asm volatile("global_load_dwordx4 %0, %1, off sc0 sc1" : "=v"(r) : "v"(p) : "memory");
  return r;
}
__device__ __forceinline__ void st128(f32x4* p, f32x4 v) {
  asm volatile("global_store_dwordx4 %0, %1, off sc0 sc1" :: "v"(p), "v"(v) : "memory");
}
__device__ __forceinline__ float ldf(const float* p) {
  float r;
  asm volatile("global_load_dword %0, %1, off sc0 sc1" : "=v"(r) : "v"(p) : "memory");
  return r;
}
__device__ __forceinline__ void stf(float* p, float v) {
  asm volatile("global_store_dword %0, %1, off sc0 sc1" :: "v"(p), "v"(v) : "memory");
}
__device__ __forceinline__ void vwait() { asm volatile("s_waitcnt vmcnt(0)" ::: "memory"); }

// poll one flag (all lanes, same addr -> one request/iter), load+wait fused
__device__ __forceinline__ void pollf(const unsigned* p, unsigned need) {
  #pragma nounroll
  for (int g = 0; g < (1 << 18); ++g) {
    unsigned v;
    asm volatile("global_load_dword %0, %1, off sc0 sc1\n\ts_waitcnt vmcnt(0)"
                 : "=v"(v) : "v"(p) : "memory");
    if (v >= need) return;
  }
}

// ---------------------------------------------------------------------------
__global__ void zero_flags_k(unsigned* f) {
  f[threadIdx.x] = 0u;
  f[threadIdx.x + 1024] = 0u;
}

// pack fp32 row-major [K][N] into f16 MFMA B-frag order
__global__ void pack_weight_k(const float* __restrict__ src, _Float16* __restrict__ dst,
                              int K, int N) {
  int idx = blockIdx.x * 256 + threadIdx.x;
  if (idx >= K * N) return;
  int k = idx / N, n = idx - k * N;
  int kt = k >> 5, q = (k >> 3) & 3, jj = k & 7;
  int nt = n >> 4, l = n & 15;
  size_t p = (((size_t)(kt * (N >> 4) + nt) * 4 + q) * 16 + l) * 8 + jj;
  dst[p] = (_Float16)src[idx];
}

// ---------------------------------------------------------------------------
// embedding: xe = x@W_emb + b_emb -> level-0 h buffer in FRAG layout
// 64 WGs x 512 thr; WG b handles t in {b, b+64, b+128, b+192}
// ---------------------------------------------------------------------------
__global__ __launch_bounds__(512, 2) void emb_k(const float* __restrict__ xin,
                                                const float* __restrict__ b_emb,
                                                char* __restrict__ ws) {
  const int tid = threadIdx.x, wave = tid >> 6, lane = tid & 63;
  const int l15 = lane & 15, quad = lane >> 4;
  const _Float16* Wp = (const _Float16*)(ws + OFF_WEMB);
  _Float16* xe = (_Float16*)(ws + OFF_HB);

  f16x8 bE[16];
  #pragma unroll
  for (int kt = 0; kt < 8; ++kt)
    #pragma unroll
    for (int i = 0; i < 2; ++i)
      bE[kt * 2 + i] = *(const f16x8*)(Wp + (((size_t)(kt * 16 + (wave * 2 + i)) * 4 + quad) * 16 + l15) * 8);
  float ber[2] = { b_emb[(wave * 2) * 16 + l15], b_emb[(wave * 2 + 1) * 16 + l15] };

  __shared__ __align__(16) _Float16 xtF[32 * 65 * 8];
  __shared__ __align__(16) _Float16 oF[32 * 65 * 8];

  for (int tt = 0; tt < 4; ++tt) {
    const int t = (int)blockIdx.x + 64 * tt;
    #pragma unroll
    for (int c = 0; c < 4; ++c) {
      int u = tid + 512 * c, s = u >> 5, kg = u & 31;
      const float* src = xin + ((size_t)s * SS + t) * DIN + kg * 8;
      f32x4 v0 = *(const f32x4*)src, v1 = *(const f32x4*)(src + 4);
      f16x8 p;
      p[0]=(_Float16)v0[0]; p[1]=(_Float16)v0[1]; p[2]=(_Float16)v0[2]; p[3]=(_Float16)v0[3];
      p[4]=(_Float16)v1[0]; p[5]=(_Float16)v1[1]; p[6]=(_Float16)v1[2]; p[7]=(_Float16)v1[3];
      *(f16x8*)(xtF + ((size_t)kg * 65 + s) * 8) = p;
    }
    __syncthreads();
    f32x4 acc[2][4] = {};
    #pragma unroll
    for (int kt = 0; kt < 8; ++kt) {
      f16x8 ax[4];
      #pragma unroll
      for (int mt = 0; mt < 4; ++mt)
        ax[mt] = *(const f16x8*)(xtF + (((size_t)(kt * 4 + quad)) * 65 + (mt * 16 + l15)) * 8);
      #pragma unroll
      for (int i = 0; i < 2; ++i)
        #pragma unroll
        for (int mt = 0; mt < 4; ++mt)
          acc[i][mt] = __builtin_amdgcn_mfma_f32_16x16x32_f16(ax[mt], bE[kt * 2 + i], acc[i][mt], 0, 0, 0);
    }
    // C -> frag-layout LDS
    #pragma unroll
    for (int i = 0; i < 2; ++i) {
      int n = (wave * 2 + i) * 16 + l15;
      int kq = n >> 3, jn = n & 7;
      #pragma unroll
      for (int mt = 0; mt < 4; ++mt)
        #pragma unroll
        for (int r = 0; r < 4; ++r) {
          int s = mt * 16 + quad * 4 + r;
          oF[((size_t)kq * 65 + s) * 8 + jn] = (_Float16)(acc[i][mt][r] + ber[i]);
        }
    }
    __syncthreads();
    // publish 16B chunks, frag-linear global: chunk u -> (kq=u>>6, s=u&63)
    #pragma unroll
    for (int c = 0; c < 4; ++c) {
      int u = tid + 512 * c, kq = u >> 6, s = u & 63;
      f32x4 v = *(const f32x4*)(oF + ((size_t)kq * 65 + s) * 8);
      *((f32x4*)(xe + (((size_t)t * 32 + kq) * 64 + s) * 8)) = v;  // plain; kernel-end flush
    }
    __syncthreads();
  }
}

// ---------------------------------------------------------------------------
// pipeline: 56 WGs (7 levels x 8 shards) x 512 thr, 1 WG/CU
// ---------------------------------------------------------------------------
__global__ __launch_bounds__(512, 2) void pipe_k(
    const float* __restrict__ mask, const float* __restrict__ b_in,
    const float* __restrict__ b1v, const float* __restrict__ bA1,
    const float* __restrict__ WA3, const float* __restrict__ bA3,
    char* __restrict__ ws, float* __restrict__ outp) {
  const int level = 1 + ((int)blockIdx.x >> 3);
  const int j     = (int)blockIdx.x & 7;
  const int tid   = threadIdx.x, wave = tid >> 6, lane = tid & 63;
  const int l15   = lane & 15, quad = lane >> 4;

  unsigned* flags = (unsigned*)(ws + OFF_FLAGS);
  unsigned* hfl   = flags + level * 64;         // own-level h flags [8]
  unsigned* hflP  = flags + (level - 1) * 64;   // prev-level h flags
  unsigned* gfl   = flags + (8 + level) * 64;   // own-level G1 flags

  const _Float16* Wp   = (const _Float16*)(ws + OFF_W);
  const _Float16* Up   = (const _Float16*)(ws + OFF_U);
  const _Float16* W1p  = (const _Float16*)(ws + OFF_W1);
  const _Float16* WA1p = (const _Float16*)(ws + OFF_WA1);
  const _Float16* UA1p = (const _Float16*)(ws + OFF_UA1);

  const f32x4* hPrev4 = (const f32x4*)((_Float16*)(ws + OFF_HB) + (size_t)(level - 1) * SS * BB * DH);
  f32x4*       hOwn4  = (f32x4*)((_Float16*)(ws + OFF_HB) + (size_t)level * SS * BB * DH);
  f32x4*       g1g4   = (f32x4*)(ws + OFF_G1 + (size_t)level * SZ_G1);
  float*       zg     = (float*)(ws + OFF_Z + (size_t)level * 4096);
  float*       nmW    = (float*)(ws + OFF_NM + (size_t)level * SZ_NM);
  float*       hvW    = (float*)(ws + OFF_HV + (size_t)level * SZ_NM);
  const float* nmR    = (const float*)(ws + OFF_NM + (size_t)(level - 1) * SZ_NM);
  const float* hvR    = (const float*)(ws + OFF_HV + (size_t)(level - 1) * SZ_NM);

  // --- weight chunks in registers ---
  const int ntG = j * 4 + (wave >> 1);   // W/U n-tile (of 32)
  const int m0  = (wave & 1) * 2;        // G1 m-tile pair
  f16x8 bW[8], bU[8];
  #pragma unroll
  for (int kt = 0; kt < 8; ++kt) {
    bW[kt] = *(const f16x8*)(Wp + (((size_t)(kt * 32 + ntG) * 4 + quad) * 16 + l15) * 8);
    bU[kt] = *(const f16x8*)(Up + (((size_t)(kt * 32 + ntG) * 4 + quad) * 16 + l15) * 8);
  }
  const int nt1 = j * 2 + (wave & 1);    // W1 n-tile (of 16)
  const int mt1 = wave >> 1;             // combine m-tile
  f16x8 b1f[16];
  #pragma unroll
  for (int kt = 0; kt < 16; ++kt)
    b1f[kt] = *(const f16x8*)(W1p + (((size_t)(kt * 16 + nt1) * 4 + quad) * 16 + l15) * 8);

  const int nG = ntG * 16 + l15;
  const int nC = nt1 * 16 + l15;
  const float bir  = b_in[nG];
  const float b1r  = b1v[nC];
  const float wa3r = WA3[(j & 3) * 16 + l15];
  const float ba1r = bA1[(j & 3) * 16 + l15];
  const float bA3v = bA3[0];

  // --- LDS (145 KB) ---
  __shared__ __align__(16) _Float16 xtF[32 * 64 * 8];   // 32 KB  xt[t] frags
  __shared__ __align__(16) _Float16 htF[32 * 64 * 8];   // 32 KB  h[t-1] frags
  __shared__ __align__(16) _Float16 g1F[64 * 64 * 8];   // 64 KB  G1 frags
  __shared__ __align__(16) _Float16 waF[16 * 64 * 8];   // 16 KB  action b-frags
  __shared__ float gB[64], gX[64], gH[64], gHv[64];

  if (j < 4) {
    for (int u = tid; u < 1024; u += 512) {
      int ktm = u >> 6, lu = u & 63, kt = ktm >> 1, m = ktm & 1;
      const _Float16* sp = (m ? UA1p : WA1p) +
          (((size_t)(kt * 4 + j) * 4 + (lu >> 4)) * 16 + (lu & 15)) * 8;
      *(f16x8*)(waF + (size_t)u * 8) = *(const f16x8*)sp;
    }
  }
  for (int i = tid; i < 32 * 64 * 8; i += 512) htF[i] = (_Float16)0;
  if (tid < 64) gHv[tid] = 0.0f;
  float hreg[4] = {0.f, 0.f, 0.f, 0.f};
  __syncthreads();

  // prologue: stage xt[0]
  if (level >= 2) pollf(hflP + wave, 1);
  __syncthreads();
  {
    f32x4 pf[4];
    #pragma unroll
    for (int c = 0; c < 4; ++c) pf[c] = ld128(hPrev4 + tid + 512 * c);  // t=0: chunks 0..2047
    vwait();
    #pragma unroll
    for (int c = 0; c < 4; ++c) ((f32x4*)xtF)[tid + 512 * c] = pf[c];
  }
  __syncthreads();

  for (int t = 0; t < SS; ++t) {
    const bool last = (t == SS - 1);

    // -- B: per-wave producer polls --
    if (t > 0) pollf(hfl + wave, (unsigned)t);
    if (level >= 2) {
      unsigned need = (unsigned)((t + 2 <= SS) ? (t + 2) : SS);
      pollf(hflP + wave, need);
    }
    // -- C: gather h[t-1] peer chunk (wave w <- shard w) --
    if (t > 0 && wave != j) {
      const f32x4* src = hOwn4 + (size_t)(t - 1) * 2048 + wave * 256;
      f32x4 hv4[4];
      #pragma unroll
      for (int it = 0; it < 4; ++it) hv4[it] = ld128(src + it * 64 + lane);
      vwait();
      #pragma unroll
      for (int it = 0; it < 4; ++it) ((f32x4*)htF)[wave * 256 + it * 64 + lane] = hv4[it];
    }
    __syncthreads();

    // -- D: G1 = lrelu(xt@W + h@U + b) own chunk; action partials --
    {
      f32x4 a0 = {}, a1 = {};
      #pragma unroll
      for (int kt = 0; kt < 8; ++kt) {
        int kq = kt * 4 + quad;
        f16x8 ax0 = *(const f16x8*)(xtF + ((size_t)(kq * 64 + m0 * 16 + l15)) * 8);
        f16x8 ax1 = *(const f16x8*)(xtF + ((size_t)(kq * 64 + (m0 + 1) * 16 + l15)) * 8);
        f16x8 ah0 = *(const f16x8*)(htF + ((size_t)(kq * 64 + m0 * 16 + l15)) * 8);
        f16x8 ah1 = *(const f16x8*)(htF + ((size_t)(kq * 64 + (m0 + 1) * 16 + l15)) * 8);
        a0 = __builtin_amdgcn_mfma_f32_16x16x32_f16(ax0, bW[kt], a0, 0, 0, 0);
        a1 = __builtin_amdgcn_mfma_f32_16x16x32_f16(ax1, bW[kt], a1, 0, 0, 0);
        a0 = __builtin_amdgcn_mfma_f32_16x16x32_f16(ah0, bU[kt], a0, 0, 0, 0);
        a1 = __builtin_amdgcn_mfma_f32_16x16x32_f16(ah1, bU[kt], a1, 0, 0, 0);
      }
      const int kqn = nG >> 3, jn = nG & 7;
      #pragma unroll
      for (int r = 0; r < 4; ++r) {
        g1F[((size_t)kqn * 64 + (m0 * 16 + quad * 4 + r)) * 8 + jn]       = (_Float16)lrelu(a0[r] + bir);
        g1F[((size_t)kqn * 64 + ((m0 + 1) * 16 + quad * 4 + r)) * 8 + jn] = (_Float16)lrelu(a1[r] + bir);
      }
      if (j < 4 && wave < 4) {  // action shard: cols [j*16, j*16+16), m-tile = wave
        f32x4 aa = {};
        #pragma unroll
        for (int kt = 0; kt < 8; ++kt) {
          int kq = kt * 4 + quad;
          f16x8 ax = *(const f16x8*)(xtF + ((size_t)(kq * 64 + wave * 16 + l15)) * 8);
          f16x8 ah = *(const f16x8*)(htF + ((size_t)(kq * 64 + wave * 16 + l15)) * 8);
          f16x8 bWa = *(const f16x8*)(waF + ((size_t)(kt * 2) * 64 + lane) * 8);
          f16x8 bUa = *(const f16x8*)(waF + ((size_t)(kt * 2 + 1) * 64 + lane) * 8);
          aa = __builtin_amdgcn_mfma_f32_16x16x32_f16(ax, bWa, aa, 0, 0, 0);
          aa = __builtin_amdgcn_mfma_f32_16x16x32_f16(ah, bUa, aa, 0, 0, 0);
        }
        #pragma unroll
        for (int r = 0; r < 4; ++r) {
          float v = lrelu(aa[r] + ba1r) * wa3r;
          v += __shfl_xor(v, 1); v += __shfl_xor(v, 2);
          v += __shfl_xor(v, 4); v += __shfl_xor(v, 8);
          if (l15 == 0) stf(&zg[j * 64 + wave * 16 + quad * 4 + r], v);
        }
      }
    }
    __syncthreads();
    // publish own G1 chunk (16B, frag-linear)
    {
      f32x4 v = ((const f32x4*)g1F)[j * 512 + tid];
      st128(g1g4 + j * 512 + tid, v);
      vwait();
    }
    __syncthreads();
    if (tid == 0)
      __hip_atomic_store(gfl + j, (unsigned)(t + 1), __ATOMIC_RELEASE, __HIP_MEMORY_SCOPE_AGENT);

    // -- E: prefetch xt[t+1] into registers (guarded by hflP >= t+2 poll) --
    f32x4 pf[4];
    if (!last) {
      const f32x4* xs = hPrev4 + (size_t)(t + 1) * 2048;
      #pragma unroll
      for (int c = 0; c < 4; ++c) pf[c] = ld128(xs + tid + 512 * c);
      vwait();
    }

    // -- G: gather G1 peer chunks (wave w <- shard w) --
    if (wave != j) {
      pollf(gfl + wave, (unsigned)(t + 1));
      const f32x4* src = g1g4 + wave * 512;
      f32x4 g4[8];
      #pragma unroll
      for (int it = 0; it < 8; ++it) g4[it] = ld128(src + it * 64 + lane);
      vwait();
      #pragma unroll
      for (int it = 0; it < 8; ++it) ((f32x4*)g1F)[wave * 512 + it * 64 + lane] = g4[it];
    }
    __syncthreads();

    // -- H: gates (wave 0) + W1 MFMA (all waves) --
    if (tid < 64) {
      int s = tid;
      float z0 = ldf(zg + s), z1 = ldf(zg + 64 + s), z2 = ldf(zg + 128 + s), z3 = ldf(zg + 192 + s);
      float pm, phv;
      if (level == 1) {
        vwait();
        float mv = mask[(size_t)s * SS + t];
        pm = mv; phv = mv;
      } else {
        size_t tn = (t + 1 < SS) ? (size_t)(t + 1) : 0;
        float pmv = ldf(nmR + tn * BB + s);
        float ph  = ldf(hvR + (size_t)t * BB + s);
        vwait();
        pm  = (t + 1 < SS) ? pmv : 1.0f;
        phv = ph;
      }
      float z    = bA3v + z0 + z1 + z2 + z3;
      float nm0  = fminf(fmaxf(0.2f * z + 0.5f, 0.0f), 1.0f);
      float lv   = last ? 1.0f : 0.0f;
      float nm   = (1.0f - lv) * (pm * phv * nm0);
      float hvp  = gHv[s], omn = 1.0f - nm;
      float both = pm * phv * omn * hvp;
      float xo   = pm * phv * (nm + omn * (1.0f - hvp));
      float ho   = (1.0f - pm * phv) * omn * hvp;
      float hv   = both + xo + ho;
      gB[s] = both; gX[s] = xo; gH[s] = ho; gHv[s] = hv;
      if (j == 0 && level < 7) {
        stf(&nmW[(size_t)t * BB + s], nm);
        stf(&hvW[(size_t)t * BB + s], hv);
      }
    }
    f32x4 c1 = {};
    #pragma unroll
    for (int kt = 0; kt < 16; ++kt) {
      f16x8 ag = *(const f16x8*)(g1F + ((size_t)((kt * 4 + quad) * 64 + mt1 * 16 + l15)) * 8);
      c1 = __builtin_amdgcn_mfma_f32_16x16x32_f16(ag, b1f[kt], c1, 0, 0, 0);
    }
    __syncthreads();

    // -- I: combine; publish own h chunk; rotate xt buffer --
    {
      const int kqc = nC >> 3, jc = nC & 7;
      #pragma unroll
      for (int r = 0; r < 4; ++r) {
        int s = mt1 * 16 + quad * 4 + r;
        float h1  = lrelu(c1[r] + b1r);
        float xtv = (float)xtF[((size_t)(kqc * 64 + s)) * 8 + jc];
        float hn  = gB[s] * h1 + gX[s] * xtv + gH[s] * hreg[r];
        hreg[r] = hn;
        htF[((size_t)(kqc * 64 + s)) * 8 + jc] = (_Float16)hn;
        if (level == 7 && last) outp[(size_t)s * DH + nC] = hn;
      }
    }
    __syncthreads();
    if (tid < 256) {
      f32x4 v = ((const f32x4*)htF)[j * 256 + tid];
      st128(hOwn4 + (size_t)t * 2048 + j * 256 + tid, v);
    }
    if (!last) {
      #pragma unroll
      for (int c = 0; c < 4; ++c) ((f32x4*)xtF)[tid + 512 * c] = pf[c];
    }
    vwait();
    __syncthreads();
    if (tid == 0)
      __hip_atomic_store(hfl + j, (unsigned)(t + 1), __ATOMIC_RELEASE, __HIP_MEMORY_SCOPE_AGENT);
  }
}

// ---------------------------------------------------------------------------
extern "C" void kernel_launch(void* const* d_in, const int* in_sizes, int n_in,
                              void* d_out, int out_size, void* d_ws, size_t ws_size,
                              hipStream_t stream) {
  const float* x     = (const float*)d_in[0];
  const float* mask  = (const float*)d_in[1];
  const float* W_emb = (const float*)d_in[3];
  const float* b_emb = (const float*)d_in[4];
  const float* W     = (const float*)d_in[5];
  const float* U     = (const float*)d_in[6];
  const float* b     = (const float*)d_in[7];
  const float* W1    = (const float*)d_in[8];
  const float* b1    = (const float*)d_in[9];
  const float* WA1   = (const float*)d_in[10];
  const float* UA1   = (const float*)d_in[11];
  const float* bA1   = (const float*)d_in[12];
  const float* WA3   = (const float*)d_in[13];
  const float* bA3   = (const float*)d_in[14];
  char* ws = (char*)d_ws;

  if (ws_size < WS_NEEDED) return;

  zero_flags_k<<<1, 1024, 0, stream>>>((unsigned*)(ws + OFF_FLAGS));
  pack_weight_k<<<(DIN * DH + 255) / 256, 256, 0, stream>>>(W_emb, (_Float16*)(ws + OFF_WEMB), DIN, DH);
  pack_weight_k<<<(DH * DNN + 255) / 256, 256, 0, stream>>>(W, (_Float16*)(ws + OFF_W), DH, DNN);
  pack_weight_k<<<(DH * DNN + 255) / 256, 256, 0, stream>>>(U, (_Float16*)(ws + OFF_U), DH, DNN);
  pack_weight_k<<<(DNN * DH + 255) / 256, 256, 0, stream>>>(W1, (_Float16*)(ws + OFF_W1), DNN, DH);
  pack_weight_k<<<(DH * DA + 255) / 256, 256, 0, stream>>>(WA1, (_Float16*)(ws + OFF_WA1), DH, DA);
  pack_weight_k<<<(DH * DA + 255) / 256, 256, 0, stream>>>(UA1, (_Float16*)(ws + OFF_UA1), DH, DA);

  emb_k<<<64, 512, 0, stream>>>(x, b_emb, ws);
  pipe_k<<<56, 512, 0, stream>>>(mask, b, b1, bA1, WA3, bA3, ws, (float*)d_out);
}